// Round 7
// baseline (27.294 us; speedup 1.0000x reference)
//
#include <hip/hip_runtime.h>

// FSNeuronDecoupled: per-element spiking scan over T=8 steps.
//   v0 = x;  for t in 0..7:  s_t = (v - theta_t > 0);  v -= h_t * s_t
//   y = sum_t d_t * s_t
// with theta_t = theta[grain(t)]^-(t+1), etc.  GRAIN = [0,0,0,0,1,1,1,1].
// Memory-bound streaming op: 4B read + 4B write per element, zero reuse.
//
// R6: restore the champion (R0 shape, 26.82 us). Six structural variants
// (TLP 8-64 blk/CU, MLP 1-8 deep, nt vs plain, flat vs grid-stride vs
// block-contiguous) all measured 26.8-28.3 us => memory roofline
// (134 MB / ~6.3 TB/s ~= 21 us) + ~5.6 us invariant replay overhead.
// R5's low-occupancy shape was latency-fragile under rocprof (83 us) —
// keep max occupancy + grid-stride, which profiles clean.

#define T_STEPS 8

typedef float f32x4 __attribute__((ext_vector_type(4)));

struct Coef {
    float th[T_STEPS], hh[T_STEPS], dd[T_STEPS];
};

__device__ __forceinline__ void make_coef(
    const float* __restrict__ d, const float* __restrict__ h,
    const float* __restrict__ theta, Coef& c)
{
    // theta_t = theta[g]^-(t+1) * TAU (TAU==1). Running reciprocal products:
    // exact powers of two for the provided inputs, matching np bit-for-bit.
    const float it0 = 1.0f / theta[0], it1 = 1.0f / theta[1];
    const float ih0 = 1.0f / h[0],     ih1 = 1.0f / h[1];
    const float id0 = 1.0f / d[0],     id1 = 1.0f / d[1];
    float pt0 = 1.0f, pt1 = 1.0f, ph0 = 1.0f, ph1 = 1.0f, pd0 = 1.0f, pd1 = 1.0f;
#pragma unroll
    for (int t = 0; t < T_STEPS; ++t) {
        pt0 *= it0; pt1 *= it1;
        ph0 *= ih0; ph1 *= ih1;
        pd0 *= id0; pd1 *= id1;
        const bool g1 = (t >= 4);           // GRAIN = [0,0,0,0,1,1,1,1]
        c.th[t] = g1 ? pt1 : pt0;
        c.hh[t] = g1 ? ph1 : ph0;
        c.dd[t] = g1 ? pd1 : pd0;
    }
}

__device__ __forceinline__ f32x4 fs_step(const f32x4 v_in, const Coef& c) {
    f32x4 v = v_in;
    f32x4 acc = {0.0f, 0.0f, 0.0f, 0.0f};
#pragma unroll
    for (int t = 0; t < T_STEPS; ++t) {
#pragma unroll
        for (int e = 0; e < 4; ++e) {
            const float s = (v[e] > c.th[t]) ? 1.0f : 0.0f;
            v[e]   -= c.hh[t] * s;
            acc[e] += c.dd[t] * s;
        }
    }
    return acc;
}

__global__ __launch_bounds__(256) void fsneuron_kernel(
    const f32x4* __restrict__ x4,
    const float* __restrict__ d,
    const float* __restrict__ h,
    const float* __restrict__ theta,
    f32x4* __restrict__ y4,
    int n4,
    const float* __restrict__ x_tail,   // scalar view for remainder
    float* __restrict__ y_tail,
    int n_total)
{
    Coef c;
    make_coef(d, h, theta, c);

    const int tid    = blockIdx.x * blockDim.x + threadIdx.x;
    const int stride = gridDim.x * blockDim.x;

    // main vectorized grid-stride loop (8 iters/thread at this size)
    for (int i = tid; i < n4; i += stride) {
        const f32x4 r = fs_step(x4[i], c);
        y4[i] = r;
    }

    // scalar tail (n_total % 4 != 0; no-op for this problem)
    for (int j = n4 * 4 + tid; j < n_total; j += stride) {
        float v = x_tail[j];
        float acc = 0.0f;
#pragma unroll
        for (int t = 0; t < T_STEPS; ++t) {
            const float s = (v > c.th[t]) ? 1.0f : 0.0f;
            v   -= c.hh[t] * s;
            acc += c.dd[t] * s;
        }
        y_tail[j] = acc;
    }
}

extern "C" void kernel_launch(void* const* d_in, const int* in_sizes, int n_in,
                              void* d_out, int out_size, void* d_ws, size_t ws_size,
                              hipStream_t stream) {
    const float* x     = (const float*)d_in[0];
    const float* d     = (const float*)d_in[1];
    const float* h     = (const float*)d_in[2];
    const float* theta = (const float*)d_in[3];
    float* y = (float*)d_out;

    const int n  = in_sizes[0];   // B*N*1 = 16,777,216
    const int n4 = n / 4;

    const int block = 256;
    int grid = (n4 + block - 1) / block;
    if (grid > 2048) grid = 2048;   // 256 CU x 8 blocks/CU; grid-stride the rest
    if (grid < 1) grid = 1;

    fsneuron_kernel<<<grid, block, 0, stream>>>(
        (const f32x4*)x, d, h, theta, (f32x4*)y, n4, x, y, n);
}